// Round 1
// baseline (1637.657 us; speedup 1.0000x reference)
//
#include <hip/hip_runtime.h>
#include <hip/hip_bf16.h>
#include <math.h>

#define NN   1024
#define CSD  384
#define CZD  128
#define HD   12
#define NOUT 1152     // 192 q + 384 kv + 144 qp + 432 kvp
#define COUTD 2112    // 192 o + 3*96 opt + 96 norm + 1536 opair

__device__ __forceinline__ float4 ld4(const float* p) {
    return *reinterpret_cast<const float4*>(p);
}

// ---------------------------------------------------------------------------
// K1a: pl[n][o] = dot(s[n], W_sel(o)) + b_sel(o), o in [0,1152)
// grid (64, 3), block 384. 16 rows per block, 384 outputs per block.
// ---------------------------------------------------------------------------
__global__ __launch_bounds__(384) void k_proj(
    const float* __restrict__ s,
    const float* __restrict__ Wq,   const float* __restrict__ bq,
    const float* __restrict__ Wkv,  const float* __restrict__ bkv,
    const float* __restrict__ Wqp,  const float* __restrict__ bqp,
    const float* __restrict__ Wkvp, const float* __restrict__ bkvp,
    float* __restrict__ pl)
{
    __shared__ float s_lds[16 * CSD];
    const int rb = blockIdx.x * 16;
    const int t  = threadIdx.x;
    for (int e = t; e < 16 * CSD; e += 384) s_lds[e] = s[(size_t)rb * CSD + e];
    __syncthreads();
    const int o = blockIdx.y * 384 + t;
    const float* W; float bias;
    if (o < 192)      { W = Wq   + (size_t)o * CSD;        bias = bq[o]; }
    else if (o < 576) { W = Wkv  + (size_t)(o-192) * CSD;  bias = bkv[o-192]; }
    else if (o < 720) { W = Wqp  + (size_t)(o-576) * CSD;  bias = bqp[o-576]; }
    else              { W = Wkvp + (size_t)(o-720) * CSD;  bias = bkvp[o-720]; }
    float acc[16];
    #pragma unroll
    for (int r = 0; r < 16; ++r) acc[r] = bias;
    for (int k = 0; k < CSD; k += 4) {
        float4 w4 = ld4(W + k);
        #pragma unroll
        for (int r = 0; r < 16; ++r) {
            float4 s4 = ld4(&s_lds[r * CSD + k]);
            acc[r] += w4.x*s4.x + w4.y*s4.y + w4.z*s4.z + w4.w*s4.w;
        }
    }
    #pragma unroll
    for (int r = 0; r < 16; ++r) pl[(size_t)(rb + r) * NOUT + o] = acc[r];
}

// ---------------------------------------------------------------------------
// K1b: split q/k/v, rotate+translate points, pack records.
// qrec/krec: (N,12,28) = [16 ch (q scaled / k), 12 ch pts(p*3+x)]
// vrec:      (N,12,40) = [16 ch v, 24 ch v_pts(p*3+x)]
// grid N, block 384
// ---------------------------------------------------------------------------
__global__ __launch_bounds__(384) void k_scatter(
    const float* __restrict__ pl, const float* __restrict__ rot,
    const float* __restrict__ trans,
    float* __restrict__ qrec, float* __restrict__ krec, float* __restrict__ vrec)
{
    const int n = blockIdx.x, t = threadIdx.x;
    __shared__ float R[9], T[3];
    if (t < 9)  R[t] = rot[n*9 + t];
    if (t >= 9 && t < 12) T[t-9] = trans[n*3 + t - 9];
    __syncthreads();
    const float s48 = 0.14433756729740643f;   // sqrt(1/48)
    const float* p = pl + (size_t)n * NOUT;
    for (int u = t; u < 768; u += 384) {
        if (u < 192) {
            int h = u >> 4, c = u & 15;
            qrec[((size_t)n*HD + h)*28 + c] = p[u] * s48;
        } else if (u < 576) {
            int e = u - 192, h = e >> 5, ee = e & 31;
            float val = p[u];
            if (ee < 16) krec[((size_t)n*HD + h)*28 + ee]      = val;
            else         vrec[((size_t)n*HD + h)*40 + (ee-16)] = val;
        } else if (u < 624) {
            int hp = u - 576;                      // 0..47 : q points
            float x = p[576 + hp], y = p[576 + 48 + hp], zz = p[576 + 96 + hp];
            float gx = R[0]*x + R[1]*y + R[2]*zz + T[0];
            float gy = R[3]*x + R[4]*y + R[5]*zz + T[1];
            float gz = R[6]*x + R[7]*y + R[8]*zz + T[2];
            int h = hp >> 2, pp = hp & 3;
            float* d = qrec + ((size_t)n*HD + h)*28 + 16 + pp*3;
            d[0] = gx; d[1] = gy; d[2] = gz;
        } else {
            int hp = u - 624;                      // 0..143 : kv points
            float x = p[720 + hp], y = p[720 + 144 + hp], zz = p[720 + 288 + hp];
            float gx = R[0]*x + R[1]*y + R[2]*zz + T[0];
            float gy = R[3]*x + R[4]*y + R[5]*zz + T[1];
            float gz = R[6]*x + R[7]*y + R[8]*zz + T[2];
            int h = hp / 12, pp = hp % 12;
            if (pp < 4) {
                float* d = krec + ((size_t)n*HD + h)*28 + 16 + pp*3;
                d[0] = gx; d[1] = gy; d[2] = gz;
            } else {
                float* d = vrec + ((size_t)n*HD + h)*40 + 16 + (pp-4)*3;
                d[0] = gx; d[1] = gy; d[2] = gz;
            }
        }
    }
}

// ---------------------------------------------------------------------------
// K2: logits L[i][h][j]. grid (N, 16), block 256: wave = 3-head group, lane = jj.
// Streams z (pass 1 of 2).
// ---------------------------------------------------------------------------
__global__ __launch_bounds__(256) void k_logits(
    const float* __restrict__ z, const float* __restrict__ qrec,
    const float* __restrict__ krec, const float* __restrict__ Wb,
    const float* __restrict__ bb, const float* __restrict__ hwin,
    const float* __restrict__ mask, float* __restrict__ L)
{
    const int i  = blockIdx.x;
    const int j0 = blockIdx.y * 64;
    const int t  = threadIdx.x;
    __shared__ float wbs[HD * CZD];
    __shared__ float qr[HD * 28];
    __shared__ float bbs[HD], hws[HD];
    const float s3 = 0.5773502691896258f;     // sqrt(1/3)
    for (int e = t; e < HD * CZD; e += 256) wbs[e] = Wb[e] * s3;
    for (int e = t; e < HD * 28;  e += 256) qr[e]  = qrec[(size_t)i*HD*28 + e];
    if (t < HD) {
        bbs[t] = bb[t] * s3;
        float x = hwin[t];
        hws[t] = -0.5f * log1pf(expf(x)) * 0.13608276348795434f;  // -0.5*softplus*sqrt(1/54)
    }
    __syncthreads();
    const int jj = t & 63;
    const int g  = t >> 6;
    const int j  = j0 + jj;
    const float* zrow = z + ((size_t)i * NN + j) * CZD;
    float acc0 = bbs[3*g+0], acc1 = bbs[3*g+1], acc2 = bbs[3*g+2];
    for (int c = 0; c < CZD; c += 4) {
        float4 zv = ld4(zrow + c);
        float4 w0 = ld4(&wbs[(3*g+0)*CZD + c]);
        float4 w1 = ld4(&wbs[(3*g+1)*CZD + c]);
        float4 w2 = ld4(&wbs[(3*g+2)*CZD + c]);
        acc0 += zv.x*w0.x + zv.y*w0.y + zv.z*w0.z + zv.w*w0.w;
        acc1 += zv.x*w1.x + zv.y*w1.y + zv.z*w1.z + zv.w*w1.w;
        acc2 += zv.x*w2.x + zv.y*w2.y + zv.z*w2.z + zv.w*w2.w;
    }
    const float mterm = 100000.0f * (mask[i] * mask[j] - 1.0f);
    float biases[3] = {acc0, acc1, acc2};
    #pragma unroll
    for (int r = 0; r < 3; ++r) {
        const int h = 3*g + r;
        const float* kr = krec + ((size_t)j*HD + h)*28;
        const float* q  = qr + h*28;
        float qk = 0.f, d2 = 0.f;
        #pragma unroll
        for (int c = 0; c < 16; ++c) qk += q[c] * kr[c];
        #pragma unroll
        for (int e = 0; e < 12; ++e) { float d = q[16+e] - kr[16+e]; d2 += d*d; }
        L[((size_t)i*HD + h)*NN + j] = biases[r] + qk + hws[h]*d2 + mterm;
    }
}

// ---------------------------------------------------------------------------
// K4: softmax + all three weighted sums. grid N, block 384 = 12 heads x 32 lanes.
// Streams z (pass 2 of 2). Writes o and o_pair straight into cat; o_pt (global
// frame) to optg.
// ---------------------------------------------------------------------------
__global__ __launch_bounds__(384) void k_accum(
    const float* __restrict__ z, const float* __restrict__ L,
    const float* __restrict__ vrec,
    float* __restrict__ cat, float* __restrict__ optg)
{
    const int i = blockIdx.x, t = threadIdx.x;
    __shared__ float Ls[HD * NN];     // 48 KB
    __shared__ float l_s[HD];
    for (int e = t; e < HD*NN/4; e += 384)
        reinterpret_cast<float4*>(Ls)[e] =
            reinterpret_cast<const float4*>(L + (size_t)i*HD*NN)[e];
    __syncthreads();
    // pass 1: softmax stats; wave wv owns heads 2wv, 2wv+1
    const int lane = t & 63, wv = t >> 6;
    for (int hh = 0; hh < 2; ++hh) {
        const int h = wv*2 + hh;
        float mx = -1e30f;
        for (int k = lane; k < NN; k += 64) mx = fmaxf(mx, Ls[h*NN + k]);
        #pragma unroll
        for (int d = 32; d; d >>= 1) mx = fmaxf(mx, __shfl_xor(mx, d));
        float sum = 0.f;
        for (int k = lane; k < NN; k += 64) {
            float pe = __expf(Ls[h*NN + k] - mx);
            Ls[h*NN + k] = pe;
            sum += pe;
        }
        #pragma unroll
        for (int d = 32; d; d >>= 1) sum += __shfl_xor(sum, d);
        if (lane == 0) l_s[h] = sum;
    }
    __syncthreads();
    // pass 2: thread = (head h, channel-quad cq)
    const int h = t >> 5, cq = t & 31;
    const float inv_l = 1.0f / l_s[h];
    float ax=0.f, ay=0.f, az=0.f, aw=0.f, a0=0.f, a1=0.f;
    const float* zr0 = z + (size_t)i * NN * CZD;
    for (int jj = 0; jj < NN; jj += 4) {
        const float4 p4 = ld4(&Ls[h*NN + jj]);
        #pragma unroll
        for (int u = 0; u < 4; ++u) {
            const float p = (u==0)?p4.x:(u==1)?p4.y:(u==2)?p4.z:p4.w;
            const float4 zv = ld4(zr0 + (size_t)(jj+u)*CZD + cq*4);
            ax += p*zv.x; ay += p*zv.y; az += p*zv.z; aw += p*zv.w;
            const float* v = vrec + ((size_t)(jj+u)*HD + h)*40;
            a0 += p * v[cq];
            float vb = (cq < 8) ? v[32 + cq] : 0.f;
            a1 += p * vb;
        }
    }
    float* cc = cat + (size_t)i * COUTD;
    float4 op; op.x = ax*inv_l; op.y = ay*inv_l; op.z = az*inv_l; op.w = aw*inv_l;
    *reinterpret_cast<float4*>(cc + 576 + h*128 + cq*4) = op;   // o_pair
    a0 *= inv_l; a1 *= inv_l;
    if (cq < 16) cc[h*16 + cq] = a0;                            // o
    else optg[((size_t)i*HD + h)*24 + (cq - 16)] = a0;          // o_pt global ch 0..15
    if (cq < 8)  optg[((size_t)i*HD + h)*24 + 16 + cq] = a1;    // o_pt global ch 16..23
}

// ---------------------------------------------------------------------------
// K5a: inverse-rotate o_pt, norms, fill cat[192..576). grid N, block 128.
// ---------------------------------------------------------------------------
__global__ __launch_bounds__(128) void k_optrot(
    const float* __restrict__ optg, const float* __restrict__ rot,
    const float* __restrict__ trans, float* __restrict__ cat)
{
    const int n = blockIdx.x, t = threadIdx.x;
    __shared__ float R[9], T[3];
    if (t < 9)  R[t] = rot[n*9 + t];
    if (t >= 9 && t < 12) T[t-9] = trans[n*3 + t-9];
    __syncthreads();
    if (t < 96) {
        const float* g = optg + (size_t)n*HD*24 + t*3;  // (h*24 + pp*3) == 3t
        float x = g[0]-T[0], y = g[1]-T[1], zz = g[2]-T[2];
        float lx = R[0]*x + R[3]*y + R[6]*zz;   // rot^T
        float ly = R[1]*x + R[4]*y + R[7]*zz;
        float lz = R[2]*x + R[5]*y + R[8]*zz;
        float nrm = sqrtf(lx*lx + ly*ly + lz*lz + 1e-8f);
        float* cc = cat + (size_t)n * COUTD;
        cc[192 + t] = lx;
        cc[288 + t] = ly;
        cc[384 + t] = lz;
        cc[480 + t] = nrm;
    }
}

// ---------------------------------------------------------------------------
// K5b: out = cat @ Wout^T + bout. grid (64,4), block 192.
// tile: 16 rows x 96 cols; thread = 4 rows x 2 cols.
// ---------------------------------------------------------------------------
__global__ __launch_bounds__(192) void k_out(
    const float* __restrict__ cat, const float* __restrict__ Wout,
    const float* __restrict__ bout, float* __restrict__ out)
{
    const int rb = blockIdx.x * 16;
    const int cb = blockIdx.y * 96;
    const int t  = threadIdx.x;
    const int c2 = t % 48;
    const int rg = t / 48;                 // 0..3 -> rows rg*4..rg*4+3
    const int c  = cb + c2*2;
    __shared__ float cs[16 * 64];
    float acc[4][2] = {};
    const float* w0 = Wout + (size_t)c * COUTD;
    const float* w1 = w0 + COUTD;
    for (int k0 = 0; k0 < COUTD; k0 += 64) {
        __syncthreads();
        for (int e = t; e < 256; e += 192) {
            int row = e >> 4, c4 = (e & 15) * 4;
            *reinterpret_cast<float4*>(&cs[row*64 + c4]) =
                ld4(cat + (size_t)(rb+row)*COUTD + k0 + c4);
        }
        __syncthreads();
        for (int kk = 0; kk < 64; kk += 4) {
            float4 a = ld4(w0 + k0 + kk);
            float4 b = ld4(w1 + k0 + kk);
            #pragma unroll
            for (int r = 0; r < 4; ++r) {
                float4 cv = ld4(&cs[(rg*4+r)*64 + kk]);
                acc[r][0] += cv.x*a.x + cv.y*a.y + cv.z*a.z + cv.w*a.w;
                acc[r][1] += cv.x*b.x + cv.y*b.y + cv.z*b.z + cv.w*b.w;
            }
        }
    }
    #pragma unroll
    for (int r = 0; r < 4; ++r) {
        out[(size_t)(rb + rg*4 + r)*CSD + c]     = acc[r][0] + bout[c];
        out[(size_t)(rb + rg*4 + r)*CSD + c + 1] = acc[r][1] + bout[c+1];
    }
}

// ---------------------------------------------------------------------------
extern "C" void kernel_launch(void* const* d_in, const int* in_sizes, int n_in,
                              void* d_out, int out_size, void* d_ws, size_t ws_size,
                              hipStream_t stream)
{
    const float* s     = (const float*)d_in[0];
    const float* z     = (const float*)d_in[1];
    const float* rot   = (const float*)d_in[2];
    const float* trans = (const float*)d_in[3];
    const float* mask  = (const float*)d_in[4];
    const float* Wq    = (const float*)d_in[5];
    const float* bq    = (const float*)d_in[6];
    const float* Wkv   = (const float*)d_in[7];
    const float* bkv   = (const float*)d_in[8];
    const float* Wqp   = (const float*)d_in[9];
    const float* bqp   = (const float*)d_in[10];
    const float* Wkvp  = (const float*)d_in[11];
    const float* bkvp  = (const float*)d_in[12];
    const float* Wb    = (const float*)d_in[13];
    const float* bb    = (const float*)d_in[14];
    const float* hw    = (const float*)d_in[15];
    const float* Wout  = (const float*)d_in[16];
    const float* bout  = (const float*)d_in[17];
    float* out = (float*)d_out;

    float* w    = (float*)d_ws;
    float* pl   = w;                                   // N*1152
    float* qrec = pl   + (size_t)NN * NOUT;            // N*12*28
    float* krec = qrec + (size_t)NN * HD * 28;         // N*12*28
    float* vrec = krec + (size_t)NN * HD * 28;         // N*12*40
    float* L    = vrec + (size_t)NN * HD * 40;         // N*12*N
    float* cat  = L    + (size_t)NN * HD * NN;         // N*2112
    float* optg = cat  + (size_t)NN * COUTD;           // N*12*24

    k_proj   <<<dim3(64, 3),  dim3(384), 0, stream>>>(s, Wq, bq, Wkv, bkv, Wqp, bqp, Wkvp, bkvp, pl);
    k_scatter<<<dim3(NN),     dim3(384), 0, stream>>>(pl, rot, trans, qrec, krec, vrec);
    k_logits <<<dim3(NN, 16), dim3(256), 0, stream>>>(z, qrec, krec, Wb, bb, hw, mask, L);
    k_accum  <<<dim3(NN),     dim3(384), 0, stream>>>(z, L, vrec, cat, optg);
    k_optrot <<<dim3(NN),     dim3(128), 0, stream>>>(optg, rot, trans, cat);
    k_out    <<<dim3(64, 4),  dim3(192), 0, stream>>>(cat, Wout, bout, out);
}

// Round 2
// 1592.614 us; speedup vs baseline: 1.0283x; 1.0283x over previous
//
#include <hip/hip_runtime.h>
#include <hip/hip_bf16.h>
#include <math.h>

#define NN   1024
#define CSD  384
#define CZD  128
#define HD   12
#define NOUT 1152     // 192 q + 384 kv + 144 qp + 432 kvp
#define COUTD 2112    // 192 o + 3*96 opt + 96 norm + 1536 opair

__device__ __forceinline__ float4 ld4(const float* p) {
    return *reinterpret_cast<const float4*>(p);
}

// ---------------------------------------------------------------------------
// K1a: pl[n][o] = dot(s[n], W_sel(o)) + b_sel(o), o in [0,1152)
// ---------------------------------------------------------------------------
__global__ __launch_bounds__(384) void k_proj(
    const float* __restrict__ s,
    const float* __restrict__ Wq,   const float* __restrict__ bq,
    const float* __restrict__ Wkv,  const float* __restrict__ bkv,
    const float* __restrict__ Wqp,  const float* __restrict__ bqp,
    const float* __restrict__ Wkvp, const float* __restrict__ bkvp,
    float* __restrict__ pl)
{
    __shared__ float s_lds[16 * CSD];
    const int rb = blockIdx.x * 16;
    const int t  = threadIdx.x;
    for (int e = t; e < 16 * CSD; e += 384) s_lds[e] = s[(size_t)rb * CSD + e];
    __syncthreads();
    const int o = blockIdx.y * 384 + t;
    const float* W; float bias;
    if (o < 192)      { W = Wq   + (size_t)o * CSD;        bias = bq[o]; }
    else if (o < 576) { W = Wkv  + (size_t)(o-192) * CSD;  bias = bkv[o-192]; }
    else if (o < 720) { W = Wqp  + (size_t)(o-576) * CSD;  bias = bqp[o-576]; }
    else              { W = Wkvp + (size_t)(o-720) * CSD;  bias = bkvp[o-720]; }
    float acc[16];
    #pragma unroll
    for (int r = 0; r < 16; ++r) acc[r] = bias;
    for (int k = 0; k < CSD; k += 4) {
        float4 w4 = ld4(W + k);
        #pragma unroll
        for (int r = 0; r < 16; ++r) {
            float4 s4 = ld4(&s_lds[r * CSD + k]);
            acc[r] += w4.x*s4.x + w4.y*s4.y + w4.z*s4.z + w4.w*s4.w;
        }
    }
    #pragma unroll
    for (int r = 0; r < 16; ++r) pl[(size_t)(rb + r) * NOUT + o] = acc[r];
}

// ---------------------------------------------------------------------------
// K1b: build augmented records.
// qa[n][h][32]: [0..15]=q*sqrt(1/48), [16..27]=qp_global*(-2*hws_h), [28]=1, pad0
// ka[n][h][32]: [0..15]=k, [16..27]=kp_global, [28]=hws_h*|kp|^2 + sqrt(1/3)*bb_h, pad0
// vrec[n][h][40]: [0..15]=v, [16..39]=vp_global
// logit = dot32(qa,ka) + z-bias + 1e5*(m_i*m_j-1)   (row-consts dropped)
// grid N, block 192 = 12h x 16e
// ---------------------------------------------------------------------------
__global__ __launch_bounds__(192) void k_scatter(
    const float* __restrict__ pl, const float* __restrict__ rot,
    const float* __restrict__ trans, const float* __restrict__ hwin,
    const float* __restrict__ bb,
    float* __restrict__ qa, float* __restrict__ ka, float* __restrict__ vrec)
{
    const int n = blockIdx.x, t = threadIdx.x;
    const int h = t >> 4, e = t & 15;
    __shared__ float R[9], T[3];
    __shared__ float kp2p[48];
    if (t < 9)  R[t] = rot[n*9 + t];
    if (t >= 9 && t < 12) T[t-9] = trans[n*3 + t - 9];
    __syncthreads();
    const float s48 = 0.14433756729740643f;   // sqrt(1/48)
    const float s3  = 0.5773502691896258f;    // sqrt(1/3)
    const float sp  = log1pf(expf(hwin[h]));
    const float hws = -0.5f * sp * 0.13608276348795434f;   // -0.5*softplus*sqrt(1/54)
    const float* p = pl + (size_t)n * NOUT;
    float* qan = qa   + ((size_t)n*HD + h)*32;
    float* kan = ka   + ((size_t)n*HD + h)*32;
    float* vn  = vrec + ((size_t)n*HD + h)*40;
    // channels
    qan[e] = p[h*16 + e] * s48;
    kan[e] = p[192 + h*32 + e];
    vn[e]  = p[192 + h*32 + 16 + e];
    if (e < 12) {              // kv point e (0..11)
        float x = p[720 + h*12 + e], y = p[720 + 144 + h*12 + e], zz = p[720 + 288 + h*12 + e];
        float gx = R[0]*x + R[1]*y + R[2]*zz + T[0];
        float gy = R[3]*x + R[4]*y + R[5]*zz + T[1];
        float gz = R[6]*x + R[7]*y + R[8]*zz + T[2];
        if (e < 4) {
            kan[16 + 3*e] = gx; kan[16 + 3*e + 1] = gy; kan[16 + 3*e + 2] = gz;
            kp2p[h*4 + e] = gx*gx + gy*gy + gz*gz;
        } else {
            vn[16 + 3*(e-4)] = gx; vn[16 + 3*(e-4) + 1] = gy; vn[16 + 3*(e-4) + 2] = gz;
        }
    } else {                   // q point p = e-12
        int pp = e - 12;
        float x = p[576 + h*4 + pp], y = p[576 + 48 + h*4 + pp], zz = p[576 + 96 + h*4 + pp];
        float gx = R[0]*x + R[1]*y + R[2]*zz + T[0];
        float gy = R[3]*x + R[4]*y + R[5]*zz + T[1];
        float gz = R[6]*x + R[7]*y + R[8]*zz + T[2];
        float c = -2.0f * hws;
        qan[16 + 3*pp] = gx*c; qan[16 + 3*pp + 1] = gy*c; qan[16 + 3*pp + 2] = gz*c;
    }
    __syncthreads();
    if (e == 0) {
        kan[28] = hws * (kp2p[h*4] + kp2p[h*4+1] + kp2p[h*4+2] + kp2p[h*4+3]) + s3 * bb[h];
        kan[29] = 0.f; kan[30] = 0.f; kan[31] = 0.f;
        qan[28] = 1.f; qan[29] = 0.f; qan[30] = 0.f; qan[31] = 0.f;
    }
}

// ---------------------------------------------------------------------------
// K2: fused flash-style attention. One block per row i; z read ONCE.
// Block 384 = 6 waves. 16 j-tiles of 64.
//   phase A (stage):  z tile -> LDS float4 slots, slot XOR-swizzled by row
//   phase B (logits): thread (jj, g): heads 2g,2g+1: z-bias from LDS + aug-dot
//   phase C (softmax): wave w: heads 2w,2w+1, online max/sum update
//   phase D (accum):  thread (h, cq): o_pair float4 + o/o_pt, rescaled by alpha
// ---------------------------------------------------------------------------
__global__ __launch_bounds__(384) void k_attn(
    const float* __restrict__ z,   const float* __restrict__ qa,
    const float* __restrict__ ka,  const float* __restrict__ vrec,
    const float* __restrict__ Wb,  const float* __restrict__ mask,
    float* __restrict__ cat, float* __restrict__ optg)
{
    const int i = blockIdx.x, t = threadIdx.x;
    __shared__ float4 zt4[64 * 32];      // 32 KB
    __shared__ float  wbs[HD * CZD];     // 6 KB, Wb * sqrt(1/3)
    __shared__ float  qas[HD * 32];      // row-i augmented q records
    __shared__ float  st[HD * 64];       // logits tile
    __shared__ float  ptile[HD * 64];    // exp(s - m)
    __shared__ float  mS[HD], lS[HD], aS[HD];

    const float s3 = 0.5773502691896258f;
    for (int e = t; e < HD * CZD; e += 384) wbs[e] = Wb[e] * s3;
    for (int e = t; e < HD * 32;  e += 384) qas[e] = qa[(size_t)i*HD*32 + e];
    if (t < HD) { mS[t] = -1e30f; lS[t] = 0.f; }
    const float mi = mask[i];

    // accumulators (phase-D layout: h = t>>5, cq = t&31)
    const int h  = t >> 5, cq = t & 31;
    float ax=0.f, ay=0.f, az=0.f, aw=0.f, a0=0.f, a1=0.f;

    // phase-B layout
    const int jj = t & 63, g = t >> 6;   // g in [0,6): heads 2g, 2g+1
    const int lane = t & 63, wv = t >> 6;

    const float* zbase = z + (size_t)i * NN * CZD;

    for (int j0 = 0; j0 < NN; j0 += 64) {
        __syncthreads();                               // zt/st/ptile reusable
        // ---- A: stage z tile (coalesced global, swizzled LDS) ----
        for (int e = t; e < 64 * 32; e += 384) {
            int row = e >> 5, s = e & 31;
            float4 v4 = ld4(zbase + (size_t)(j0 + row) * CZD + s * 4);
            zt4[row * 32 + (s ^ (row & 31))] = v4;
        }
        __syncthreads();
        // ---- B: logits for heads 2g, 2g+1, column j0+jj ----
        {
            const int h0 = 2*g, h1 = 2*g + 1;
            float b0 = 0.f, b1 = 0.f;
            const int rbase = jj * 32, rx = jj & 31;
            #pragma unroll 8
            for (int s = 0; s < 32; ++s) {
                float4 zv = zt4[rbase + (s ^ rx)];
                float4 w0 = ld4(&wbs[h0 * CZD + 4*s]);
                float4 w1 = ld4(&wbs[h1 * CZD + 4*s]);
                b0 += zv.x*w0.x + zv.y*w0.y + zv.z*w0.z + zv.w*w0.w;
                b1 += zv.x*w1.x + zv.y*w1.y + zv.z*w1.z + zv.w*w1.w;
            }
            const int j = j0 + jj;
            const float* ka0 = ka + ((size_t)j*HD + h0)*32;
            const float* ka1 = ka + ((size_t)j*HD + h1)*32;
            float q0 = 0.f, q1 = 0.f;
            #pragma unroll
            for (int s = 0; s < 8; ++s) {
                float4 k0 = ld4(ka0 + 4*s);
                float4 k1 = ld4(ka1 + 4*s);
                float4 a0v = ld4(&qas[h0*32 + 4*s]);
                float4 a1v = ld4(&qas[h1*32 + 4*s]);
                q0 += k0.x*a0v.x + k0.y*a0v.y + k0.z*a0v.z + k0.w*a0v.w;
                q1 += k1.x*a1v.x + k1.y*a1v.y + k1.z*a1v.z + k1.w*a1v.w;
            }
            const float mterm = 100000.0f * (mi * mask[j] - 1.0f);
            st[h0*64 + jj] = b0 + q0 + mterm;
            st[h1*64 + jj] = b1 + q1 + mterm;
        }
        __syncthreads();
        // ---- C: online softmax (wave wv handles heads 2wv, 2wv+1) ----
        #pragma unroll
        for (int hh = 0; hh < 2; ++hh) {
            const int hs = 2*wv + hh;
            float sv = st[hs*64 + lane];
            float mx = sv;
            #pragma unroll
            for (int d = 32; d; d >>= 1) mx = fmaxf(mx, __shfl_xor(mx, d));
            float mold = mS[hs];
            float mnew = fmaxf(mold, mx);
            float al   = __expf(mold - mnew);
            float pe   = __expf(sv - mnew);
            ptile[hs*64 + lane] = pe;
            float sum = pe;
            #pragma unroll
            for (int d = 32; d; d >>= 1) sum += __shfl_xor(sum, d);
            if (lane == 0) { mS[hs] = mnew; lS[hs] = lS[hs]*al + sum; aS[hs] = al; }
        }
        __syncthreads();
        // ---- D: accumulate (thread = (h, cq)) ----
        {
            const float al = aS[h];
            ax *= al; ay *= al; az *= al; aw *= al; a0 *= al; a1 *= al;
            for (int u = 0; u < 64; u += 4) {
                float4 p4 = ld4(&ptile[h*64 + u]);
                #pragma unroll
                for (int q = 0; q < 4; ++q) {
                    const int jr = u + q;
                    const float pw = (q==0)?p4.x:(q==1)?p4.y:(q==2)?p4.z:p4.w;
                    float4 zv = zt4[jr * 32 + (cq ^ (jr & 31))];
                    ax += pw*zv.x; ay += pw*zv.y; az += pw*zv.z; aw += pw*zv.w;
                    const float* v = vrec + ((size_t)(j0 + jr)*HD + h)*40;
                    a0 += pw * v[cq];
                    float vb = (cq < 8) ? v[32 + cq] : 0.f;
                    a1 += pw * vb;
                }
            }
        }
    }
    // ---- epilogue ----
    const float inv = 1.0f / lS[h];
    float* cc = cat + (size_t)i * COUTD;
    float4 op; op.x = ax*inv; op.y = ay*inv; op.z = az*inv; op.w = aw*inv;
    *reinterpret_cast<float4*>(cc + 576 + h*128 + cq*4) = op;     // o_pair
    a0 *= inv; a1 *= inv;
    if (cq < 16) cc[h*16 + cq] = a0;                              // o
    else optg[((size_t)i*HD + h)*24 + (cq - 16)] = a0;            // o_pt glob 0..15
    if (cq < 8)  optg[((size_t)i*HD + h)*24 + 16 + cq] = a1;      // o_pt glob 16..23
}

// ---------------------------------------------------------------------------
// K5a: inverse-rotate o_pt, norms, fill cat[192..576).
// ---------------------------------------------------------------------------
__global__ __launch_bounds__(128) void k_optrot(
    const float* __restrict__ optg, const float* __restrict__ rot,
    const float* __restrict__ trans, float* __restrict__ cat)
{
    const int n = blockIdx.x, t = threadIdx.x;
    __shared__ float R[9], T[3];
    if (t < 9)  R[t] = rot[n*9 + t];
    if (t >= 9 && t < 12) T[t-9] = trans[n*3 + t-9];
    __syncthreads();
    if (t < 96) {
        const float* g = optg + (size_t)n*HD*24 + t*3;
        float x = g[0]-T[0], y = g[1]-T[1], zz = g[2]-T[2];
        float lx = R[0]*x + R[3]*y + R[6]*zz;
        float ly = R[1]*x + R[4]*y + R[7]*zz;
        float lz = R[2]*x + R[5]*y + R[8]*zz;
        float nrm = sqrtf(lx*lx + ly*ly + lz*lz + 1e-8f);
        float* cc = cat + (size_t)n * COUTD;
        cc[192 + t] = lx;
        cc[288 + t] = ly;
        cc[384 + t] = lz;
        cc[480 + t] = nrm;
    }
}

// ---------------------------------------------------------------------------
// K5b: out = cat @ Wout^T + bout. grid (64,4), block 192.
// ---------------------------------------------------------------------------
__global__ __launch_bounds__(192) void k_out(
    const float* __restrict__ cat, const float* __restrict__ Wout,
    const float* __restrict__ bout, float* __restrict__ out)
{
    const int rb = blockIdx.x * 16;
    const int cb = blockIdx.y * 96;
    const int t  = threadIdx.x;
    const int c2 = t % 48;
    const int rg = t / 48;
    const int c  = cb + c2*2;
    __shared__ float cs[16 * 64];
    float acc[4][2] = {};
    const float* w0 = Wout + (size_t)c * COUTD;
    const float* w1 = w0 + COUTD;
    for (int k0 = 0; k0 < COUTD; k0 += 64) {
        __syncthreads();
        for (int e = t; e < 256; e += 192) {
            int row = e >> 4, c4 = (e & 15) * 4;
            *reinterpret_cast<float4*>(&cs[row*64 + c4]) =
                ld4(cat + (size_t)(rb+row)*COUTD + k0 + c4);
        }
        __syncthreads();
        for (int kk = 0; kk < 64; kk += 4) {
            float4 a = ld4(w0 + k0 + kk);
            float4 b = ld4(w1 + k0 + kk);
            #pragma unroll
            for (int r = 0; r < 4; ++r) {
                float4 cv = ld4(&cs[(rg*4+r)*64 + kk]);
                acc[r][0] += cv.x*a.x + cv.y*a.y + cv.z*a.z + cv.w*a.w;
                acc[r][1] += cv.x*b.x + cv.y*b.y + cv.z*b.z + cv.w*b.w;
            }
        }
    }
    #pragma unroll
    for (int r = 0; r < 4; ++r) {
        out[(size_t)(rb + rg*4 + r)*CSD + c]     = acc[r][0] + bout[c];
        out[(size_t)(rb + rg*4 + r)*CSD + c + 1] = acc[r][1] + bout[c+1];
    }
}

// ---------------------------------------------------------------------------
extern "C" void kernel_launch(void* const* d_in, const int* in_sizes, int n_in,
                              void* d_out, int out_size, void* d_ws, size_t ws_size,
                              hipStream_t stream)
{
    const float* s     = (const float*)d_in[0];
    const float* z     = (const float*)d_in[1];
    const float* rot   = (const float*)d_in[2];
    const float* trans = (const float*)d_in[3];
    const float* mask  = (const float*)d_in[4];
    const float* Wq    = (const float*)d_in[5];
    const float* bq    = (const float*)d_in[6];
    const float* Wkv   = (const float*)d_in[7];
    const float* bkv   = (const float*)d_in[8];
    const float* Wqp   = (const float*)d_in[9];
    const float* bqp   = (const float*)d_in[10];
    const float* Wkvp  = (const float*)d_in[11];
    const float* bkvp  = (const float*)d_in[12];
    const float* Wb    = (const float*)d_in[13];
    const float* bb    = (const float*)d_in[14];
    const float* hw    = (const float*)d_in[15];
    const float* Wout  = (const float*)d_in[16];
    const float* bout  = (const float*)d_in[17];
    float* out = (float*)d_out;

    float* w    = (float*)d_ws;
    float* pl   = w;                                   // N*1152
    float* qa   = pl   + (size_t)NN * NOUT;            // N*12*32
    float* ka   = qa   + (size_t)NN * HD * 32;         // N*12*32
    float* vrec = ka   + (size_t)NN * HD * 32;         // N*12*40
    float* cat  = vrec + (size_t)NN * HD * 40;         // N*2112
    float* optg = cat  + (size_t)NN * COUTD;           // N*12*24

    k_proj   <<<dim3(64, 3),  dim3(384), 0, stream>>>(s, Wq, bq, Wkv, bkv, Wqp, bqp, Wkvp, bkvp, pl);
    k_scatter<<<dim3(NN),     dim3(192), 0, stream>>>(pl, rot, trans, hw, bb, qa, ka, vrec);
    k_attn   <<<dim3(NN),     dim3(384), 0, stream>>>(z, qa, ka, vrec, Wb, mask, cat, optg);
    k_optrot <<<dim3(NN),     dim3(128), 0, stream>>>(optg, rot, trans, cat);
    k_out    <<<dim3(64, 4),  dim3(192), 0, stream>>>(cat, Wout, bout, out);
}